// Round 1
// baseline (1071.517 us; speedup 1.0000x reference)
//
#include <hip/hip_runtime.h>
#include <hip/hip_bf16.h>
#include <math.h>

#define B_SZ 32
#define T_SZ 2048
#define H_SZ 1024
#define U_SZ 1024

typedef __attribute__((ext_vector_type(8))) short bf16x8;   // 8 bf16 = 4 VGPRs
typedef __attribute__((ext_vector_type(4))) float f32x4;    // mfma 16x16 accumulator

// fp32 -> bf16 round-to-nearest-even
__device__ inline unsigned short f2bf(float f) {
  union { float f; unsigned int u; } x; x.f = f;
  unsigned int r = x.u + 0x7FFFu + ((x.u >> 16) & 1u);
  return (unsigned short)(r >> 16);
}

// ---------------------------------------------------------------------------
// W2 [H][U] fp32  ->  W2t [U][H] bf16 (transposed so B-fragments are
// k-contiguous in LDS -> ds_read_b128 instead of scalar ds_read_u16)
// ---------------------------------------------------------------------------
__global__ void k_prep_w2t(const float* __restrict__ W2, unsigned short* __restrict__ W2t) {
  __shared__ unsigned short tile[64][65];   // [u_local][h_local], +1 pad
  const int bu = blockIdx.x;  // U/64 = 16
  const int bh = blockIdx.y;  // H/64 = 16
  const int tc = threadIdx.x & 63;
  const int tr = threadIdx.x >> 6;          // 0..3
  #pragma unroll
  for (int i = 0; i < 16; ++i) {
    const int hl = tr + i * 4;
    const float v = W2[(size_t)(bh * 64 + hl) * U_SZ + bu * 64 + tc];
    tile[tc][hl] = f2bf(v);                 // transposed store
  }
  __syncthreads();
  #pragma unroll
  for (int i = 0; i < 16; ++i) {
    const int ul = tr + i * 4;
    W2t[(size_t)(bu * 64 + ul) * H_SZ + bh * 64 + tc] = tile[ul][tc];
  }
}

// ---------------------------------------------------------------------------
// qq[b][u] = dec[b]·W1[:,u] + b1[u] + b2[u]   (fp32, tiny)
// ---------------------------------------------------------------------------
__global__ void k_qq(const float* __restrict__ dec, const float* __restrict__ W1,
                     const float* __restrict__ b1, const float* __restrict__ b2,
                     float* __restrict__ qq) {
  const int u = blockIdx.x * 256 + threadIdx.x;
  const int b = blockIdx.y;
  float acc = 0.0f;
  #pragma unroll 8
  for (int h = 0; h < H_SZ; ++h)
    acc += dec[b * H_SZ + h] * W1[(size_t)h * U_SZ + u];
  qq[b * U_SZ + u] = acc + b1[u] + b2[u];
}

// ---------------------------------------------------------------------------
// Fused: score[m] = sum_u tanh(enc@W2 + qq) * V[u]  for 64 rows per block.
// BM=64, U-loop of 4 x BN=256, BK=32. 4 waves, each 64 rows x 64 cols
// (4x4 mfma_f32_16x16x32_bf16). A converted fp32->bf16 during staging.
// LDS row stride 40 (80 B): b128 frag reads are 16B-aligned, 2-way bank
// aliasing only (free per m136).
// ---------------------------------------------------------------------------
__global__ __launch_bounds__(256) void k_gemm_score(
    const float* __restrict__ enc, const unsigned short* __restrict__ W2t,
    const float* __restrict__ qq, const float* __restrict__ Vv,
    float* __restrict__ score)
{
  __shared__ unsigned short Al[64 * 40];    // 5 KB
  __shared__ unsigned short Bl[256 * 40];   // 20 KB
  __shared__ float scoreS[64];

  const int tid  = threadIdx.x;
  const int wave = tid >> 6;
  const int lane = tid & 63;
  const int quad = lane >> 4;
  const int l16  = lane & 15;
  const int m0   = blockIdx.x * 64;     // global row base (b*2048 + t)
  const int b    = m0 >> 11;            // all 64 rows share one b

  if (tid < 64) scoreS[tid] = 0.0f;

  const int arow = tid >> 3;            // 0..31
  const int acol = (tid & 7) * 4;       // 0,4,..,28
  const int brow = tid >> 2;            // 0..63
  const int bcol = (tid & 3) * 8;       // 0,8,16,24

  for (int ut = 0; ut < 4; ++ut) {
    const int u0 = ut * 256;
    f32x4 acc[4][4];
    #pragma unroll
    for (int rt = 0; rt < 4; ++rt)
      #pragma unroll
      for (int ct = 0; ct < 4; ++ct)
        #pragma unroll
        for (int r = 0; r < 4; ++r) acc[rt][ct][r] = 0.0f;

    for (int kk = 0; kk < H_SZ; kk += 32) {
      __syncthreads();   // previous iter's frag reads / scoreS init done
      // ---- stage A: 64x32 fp32 -> bf16 ----
      #pragma unroll
      for (int it = 0; it < 2; ++it) {
        const int row = it * 32 + arow;
        const float4 a = *(const float4*)&enc[(size_t)(m0 + row) * H_SZ + kk + acol];
        const unsigned long long packed =
            (unsigned long long)f2bf(a.x)
          | ((unsigned long long)f2bf(a.y) << 16)
          | ((unsigned long long)f2bf(a.z) << 32)
          | ((unsigned long long)f2bf(a.w) << 48);
        *(unsigned long long*)&Al[row * 40 + acol] = packed;
      }
      // ---- stage B: 256x32 bf16 from W2t ----
      #pragma unroll
      for (int it = 0; it < 4; ++it) {
        const int u = it * 64 + brow;
        const uint4 v = *(const uint4*)&W2t[(size_t)(u0 + u) * H_SZ + kk + bcol];
        *(uint2*)&Bl[u * 40 + bcol]     = make_uint2(v.x, v.y);
        *(uint2*)&Bl[u * 40 + bcol + 4] = make_uint2(v.z, v.w);
      }
      __syncthreads();
      // ---- fragments + MFMA ----
      bf16x8 af[4], bfr[4];
      #pragma unroll
      for (int rt = 0; rt < 4; ++rt)
        af[rt] = *(const bf16x8*)&Al[(rt * 16 + l16) * 40 + quad * 8];
      #pragma unroll
      for (int ct = 0; ct < 4; ++ct)
        bfr[ct] = *(const bf16x8*)&Bl[(wave * 64 + ct * 16 + l16) * 40 + quad * 8];
      #pragma unroll
      for (int rt = 0; rt < 4; ++rt)
        #pragma unroll
        for (int ct = 0; ct < 4; ++ct)
          acc[rt][ct] = __builtin_amdgcn_mfma_f32_16x16x32_bf16(
              af[rt], bfr[ct], acc[rt][ct], 0, 0, 0);
    }

    // ---- fused epilogue: tanh(acc+qq)*V, reduce over this U-tile's cols ----
    // C/D layout: col = l16 (+16*ct), row = quad*4 + r (+16*rt)
    float part[4][4];
    #pragma unroll
    for (int rt = 0; rt < 4; ++rt)
      #pragma unroll
      for (int r = 0; r < 4; ++r) part[rt][r] = 0.0f;
    #pragma unroll
    for (int ct = 0; ct < 4; ++ct) {
      const int u = u0 + wave * 64 + ct * 16 + l16;
      const float qv = qq[b * U_SZ + u];
      const float vv = Vv[u];
      #pragma unroll
      for (int rt = 0; rt < 4; ++rt)
        #pragma unroll
        for (int r = 0; r < 4; ++r)
          part[rt][r] += tanhf(acc[rt][ct][r] + qv) * vv;
    }
    // reduce over the 16 lanes of each quad (cols)
    #pragma unroll
    for (int rt = 0; rt < 4; ++rt)
      #pragma unroll
      for (int r = 0; r < 4; ++r) {
        float p = part[rt][r];
        p += __shfl_xor(p, 1);
        p += __shfl_xor(p, 2);
        p += __shfl_xor(p, 4);
        p += __shfl_xor(p, 8);
        part[rt][r] = p;
      }
    if (l16 == 0) {
      #pragma unroll
      for (int rt = 0; rt < 4; ++rt)
        #pragma unroll
        for (int r = 0; r < 4; ++r)
          atomicAdd(&scoreS[rt * 16 + quad * 4 + r], part[rt][r]);
    }
  }
  __syncthreads();
  if (tid < 64) score[m0 + tid] = scoreS[tid];
}

// ---------------------------------------------------------------------------
// softmax over T per batch. bv omitted (constant shift, softmax-invariant).
// ---------------------------------------------------------------------------
__global__ void k_softmax(const float* __restrict__ score, float* __restrict__ attn) {
  const int b = blockIdx.x;
  const int tid = threadIdx.x;   // 256
  __shared__ float wmax[4], wsum[4];
  const float* s = score + b * T_SZ;
  float v[8];
  float lmax = -INFINITY;
  #pragma unroll
  for (int i = 0; i < 8; ++i) { v[i] = s[tid + i * 256]; lmax = fmaxf(lmax, v[i]); }
  #pragma unroll
  for (int m = 1; m <= 32; m <<= 1) lmax = fmaxf(lmax, __shfl_xor(lmax, m));
  if ((tid & 63) == 0) wmax[tid >> 6] = lmax;
  __syncthreads();
  const float gmax = fmaxf(fmaxf(wmax[0], wmax[1]), fmaxf(wmax[2], wmax[3]));
  float lsum = 0.0f;
  #pragma unroll
  for (int i = 0; i < 8; ++i) { v[i] = __expf(v[i] - gmax); lsum += v[i]; }
  #pragma unroll
  for (int m = 1; m <= 32; m <<= 1) lsum += __shfl_xor(lsum, m);
  if ((tid & 63) == 0) wsum[tid >> 6] = lsum;
  __syncthreads();
  const float inv = 1.0f / (wsum[0] + wsum[1] + wsum[2] + wsum[3]);
  #pragma unroll
  for (int i = 0; i < 8; ++i) attn[b * T_SZ + tid + i * 256] = v[i] * inv;
}

// ---------------------------------------------------------------------------
// context[b][h] = sum_t attn[b][t] * enc[b][t][h]   (fp32, memory-bound)
// grid (8 t-chunks, 4 h-chunks, 32 b); partial sums via global atomicAdd.
// ---------------------------------------------------------------------------
__global__ void k_context(const float* __restrict__ enc, const float* __restrict__ attn,
                          float* __restrict__ ctx) {
  const int tcx = blockIdx.x;   // 0..7
  const int hc  = blockIdx.y;   // 0..3
  const int b   = blockIdx.z;   // 0..31
  const int h   = hc * 256 + threadIdx.x;
  const float* e = enc + ((size_t)b * T_SZ + tcx * 256) * H_SZ + h;
  const float* a = attn + b * T_SZ + tcx * 256;
  float a0 = 0, a1 = 0, a2 = 0, a3 = 0;
  for (int t = 0; t < 256; t += 4) {
    a0 += a[t]     * e[(size_t)t * H_SZ];
    a1 += a[t + 1] * e[(size_t)(t + 1) * H_SZ];
    a2 += a[t + 2] * e[(size_t)(t + 2) * H_SZ];
    a3 += a[t + 3] * e[(size_t)(t + 3) * H_SZ];
  }
  atomicAdd(&ctx[b * H_SZ + h], (a0 + a1) + (a2 + a3));
}

// ---------------------------------------------------------------------------
extern "C" void kernel_launch(void* const* d_in, const int* in_sizes, int n_in,
                              void* d_out, int out_size, void* d_ws, size_t ws_size,
                              hipStream_t stream) {
  const float* dec = (const float*)d_in[0];
  const float* enc = (const float*)d_in[1];
  const float* W1  = (const float*)d_in[2];
  const float* b1  = (const float*)d_in[3];
  const float* W2  = (const float*)d_in[4];
  const float* b2  = (const float*)d_in[5];
  const float* Vv  = (const float*)d_in[6];
  // d_in[7] = bv: constant shift inside softmax -> no effect on outputs.

  // workspace layout (~2.4 MB)
  unsigned short* W2t = (unsigned short*)d_ws;                                  // 2 MB
  float* qq    = (float*)((char*)d_ws + (2u << 20));                            // 128 KB
  float* score = (float*)((char*)d_ws + (2u << 20) + (128u << 10));             // 256 KB

  float* ctx  = (float*)d_out;                  // [32,1024]
  float* attn = (float*)d_out + B_SZ * H_SZ;    // [32,2048,1]

  hipMemsetAsync(ctx, 0, B_SZ * H_SZ * sizeof(float), stream);  // atomicAdd target
  k_prep_w2t<<<dim3(16, 16), 256, 0, stream>>>(W2, W2t);
  k_qq<<<dim3(4, 32), 256, 0, stream>>>(dec, W1, b1, b2, qq);
  k_gemm_score<<<1024, 256, 0, stream>>>(enc, W2t, qq, Vv, score);
  k_softmax<<<32, 256, 0, stream>>>(score, attn);
  k_context<<<dim3(8, 4, 32), 256, 0, stream>>>(enc, attn, ctx);
}

// Round 2
// 654.487 us; speedup vs baseline: 1.6372x; 1.6372x over previous
//
#include <hip/hip_runtime.h>
#include <hip/hip_bf16.h>
#include <math.h>

#define B_SZ 32
#define T_SZ 2048
#define H_SZ 1024
#define U_SZ 1024

#define BM 128
#define BN 128
#define BK 64

typedef __attribute__((ext_vector_type(8))) short bf16x8;   // 8 bf16 = 4 VGPRs
typedef __attribute__((ext_vector_type(4))) float f32x4;    // mfma 16x16 accumulator

// fp32 -> bf16 round-to-nearest-even
__device__ __forceinline__ unsigned int f2bf(float f) {
  union { float f; unsigned int u; } x; x.f = f;
  unsigned int r = x.u + 0x7FFFu + ((x.u >> 16) & 1u);
  return r >> 16;
}

// async global -> LDS, 16 B per lane. LDS dest = wave-uniform base + lane*16.
__device__ __forceinline__ void async_cp16(const unsigned short* g, unsigned short* l) {
  __builtin_amdgcn_global_load_lds(
      (const __attribute__((address_space(1))) unsigned int*)g,
      (__attribute__((address_space(3))) unsigned int*)l, 16, 0, 0);
}

__device__ __forceinline__ float fast_tanh(float x) {
  const float e = __expf(x + x);
  return (e - 1.0f) * __builtin_amdgcn_rcpf(e + 1.0f);
}

// ---------------------------------------------------------------------------
// enc fp32 [B*T*H] -> bf16, 8 elems/thread
// ---------------------------------------------------------------------------
__global__ void k_cvt_enc(const float* __restrict__ enc, unsigned short* __restrict__ encb) {
  const size_t i = ((size_t)blockIdx.x * 256 + threadIdx.x) * 8;
  const float4 a = *(const float4*)(enc + i);
  const float4 b = *(const float4*)(enc + i + 4);
  uint4 o;
  o.x = f2bf(a.x) | (f2bf(a.y) << 16);
  o.y = f2bf(a.z) | (f2bf(a.w) << 16);
  o.z = f2bf(b.x) | (f2bf(b.y) << 16);
  o.w = f2bf(b.z) | (f2bf(b.w) << 16);
  *(uint4*)(encb + i) = o;
}

// ---------------------------------------------------------------------------
// W2 [H][U] fp32 -> W2t [U][H] bf16 (transposed: B-fragments k-contiguous)
// ---------------------------------------------------------------------------
__global__ void k_prep_w2t(const float* __restrict__ W2, unsigned short* __restrict__ W2t) {
  __shared__ unsigned short tile[64][65];
  const int bu = blockIdx.x, bh = blockIdx.y;
  const int tc = threadIdx.x & 63, tr = threadIdx.x >> 6;
  #pragma unroll
  for (int i = 0; i < 16; ++i) {
    const int hl = tr + i * 4;
    tile[tc][hl] = (unsigned short)f2bf(W2[(size_t)(bh * 64 + hl) * U_SZ + bu * 64 + tc]);
  }
  __syncthreads();
  #pragma unroll
  for (int i = 0; i < 16; ++i) {
    const int ul = tr + i * 4;
    W2t[(size_t)(bu * 64 + ul) * H_SZ + bh * 64 + tc] = tile[ul][tc];
  }
}

// ---------------------------------------------------------------------------
// qq[b][u] = dec[b]·W1[:,u] + b1[u] + b2[u]
// grid (16 u-tiles, 32 b); 256 thr = 64 u x 4 h-quarters; LDS reduce.
// ---------------------------------------------------------------------------
__global__ __launch_bounds__(256) void k_qq(
    const float* __restrict__ dec, const float* __restrict__ W1,
    const float* __restrict__ b1, const float* __restrict__ b2,
    float* __restrict__ qq) {
  __shared__ float red[4][64];
  const int ul = threadIdx.x & 63;
  const int hq = threadIdx.x >> 6;
  const int u  = blockIdx.x * 64 + ul;
  const int b  = blockIdx.y;
  const float* dh = dec + b * H_SZ + hq * 256;
  const float* w  = W1 + (size_t)(hq * 256) * U_SZ + u;
  float acc = 0.0f;
  #pragma unroll 8
  for (int h = 0; h < 256; ++h) acc += dh[h] * w[(size_t)h * U_SZ];
  red[hq][ul] = acc;
  __syncthreads();
  if (threadIdx.x < 64) {
    const float s = red[0][ul] + red[1][ul] + red[2][ul] + red[3][ul];
    qq[b * U_SZ + u] = s + b1[u] + b2[u];
  }
}

// ---------------------------------------------------------------------------
// Fused GEMM + tanh·V reduce: score[m] = sum_u tanh((enc@W2)[m][u] + qq) * V[u]
// BM=128 rows/block, ut-loop over 8 BN=128 col tiles, BK=64.
// 4 waves in 2x2: wave (wr,wc) computes 64x64 via 4x4 mfma_f32_16x16x32_bf16.
// LDS layout (A and B identical): row-major [row][64k], row stride 128 B,
// 8 chunks of 16 B per row, stored chunk' = (chunk + row) & 7  (XOR-rotate
// swizzle -> frag ds_read_b128 hits 8 distinct bank groups = conflict-free).
// Staged with global_load_lds(16B): slot s = (inst*4+wave)*64+lane writes LDS
// bytes [s*16, s*16+16) = row s>>3, chunk' s&7 -> lane fetches source chunk
// ((s&7) - row) & 7 of that row (same 128 B global region, rotated order).
// ---------------------------------------------------------------------------
template <bool PRE_BF16>
__global__ __launch_bounds__(256) void k_gemm_score(
    const unsigned short* __restrict__ encb,   // bf16 enc (fast path)
    const float* __restrict__ encf,            // fp32 enc (fallback path)
    const unsigned short* __restrict__ W2t,
    const float* __restrict__ qq, const float* __restrict__ Vv,
    float* __restrict__ score)
{
  __shared__ unsigned short Al[BM * BK];   // 16 KB
  __shared__ unsigned short Bl[BN * BK];   // 16 KB
  __shared__ float scoreS[BM];

  const int tid  = threadIdx.x;
  const int wave = tid >> 6;
  const int lane = tid & 63;
  const int quad = lane >> 4;
  const int l16  = lane & 15;
  const int wr   = wave >> 1;      // row half
  const int wc   = wave & 1;       // col half
  const int m0   = blockIdx.x * BM;
  const int b    = m0 >> 11;       // all BM rows share one batch (2048 % 128 == 0)

  if (tid < BM) scoreS[tid] = 0.0f;

  // staging address precompute (A via global_load_lds when PRE_BF16)
  size_t aoff[4], boff[4];
  unsigned short *dstA[4], *dstB[4];
  #pragma unroll
  for (int i = 0; i < 4; ++i) {
    const int slot = (i * 4 + wave) * 64 + lane;
    const int r = slot >> 3;
    const int c = ((slot & 7) - r) & 7;          // source chunk (swizzle)
    aoff[i] = (size_t)(m0 + r) * H_SZ + c * 8;
    boff[i] = (size_t)r * H_SZ + c * 8;          // u_local = r
    dstA[i] = &Al[(i * 4 + wave) * 512];         // wave-uniform, +lane*16B by HW
    dstB[i] = &Bl[(i * 4 + wave) * 512];
  }

  // fragment LDS element offsets: row*64 + ((chunk + row)&7)*8
  const int ar[4] = { wr * 64 + 0 * 16 + l16, wr * 64 + 1 * 16 + l16,
                      wr * 64 + 2 * 16 + l16, wr * 64 + 3 * 16 + l16 };
  const int bu[4] = { wc * 64 + 0 * 16 + l16, wc * 64 + 1 * 16 + l16,
                      wc * 64 + 2 * 16 + l16, wc * 64 + 3 * 16 + l16 };

  for (int ut = 0; ut < 8; ++ut) {
    const int u0 = ut * BN;
    f32x4 acc[4][4];
    #pragma unroll
    for (int rt = 0; rt < 4; ++rt)
      #pragma unroll
      for (int ct = 0; ct < 4; ++ct)
        #pragma unroll
        for (int r = 0; r < 4; ++r) acc[rt][ct][r] = 0.0f;

    for (int kk = 0; kk < H_SZ; kk += BK) {
      __syncthreads();
      if constexpr (PRE_BF16) {
        #pragma unroll
        for (int i = 0; i < 4; ++i) async_cp16(encb + aoff[i] + kk, dstA[i]);
      } else {
        #pragma unroll
        for (int i = 0; i < 4; ++i) {
          const int slot = i * 256 + tid;
          const int r = slot >> 3;
          const int c = ((slot & 7) - r) & 7;
          const float* src = encf + (size_t)(m0 + r) * H_SZ + kk + c * 8;
          const float4 x = *(const float4*)src;
          const float4 y = *(const float4*)(src + 4);
          uint4 o;
          o.x = f2bf(x.x) | (f2bf(x.y) << 16);
          o.y = f2bf(x.z) | (f2bf(x.w) << 16);
          o.z = f2bf(y.x) | (f2bf(y.y) << 16);
          o.w = f2bf(y.z) | (f2bf(y.w) << 16);
          *(uint4*)&Al[slot * 8] = o;
        }
      }
      #pragma unroll
      for (int i = 0; i < 4; ++i)
        async_cp16(W2t + (size_t)u0 * H_SZ + boff[i] + kk, dstB[i]);
      __syncthreads();

      #pragma unroll
      for (int h = 0; h < 2; ++h) {
        bf16x8 af[4], bfr[4];
        #pragma unroll
        for (int rt = 0; rt < 4; ++rt)
          af[rt] = *(const bf16x8*)&Al[ar[rt] * 64 + ((h * 4 + quad + ar[rt]) & 7) * 8];
        #pragma unroll
        for (int ct = 0; ct < 4; ++ct)
          bfr[ct] = *(const bf16x8*)&Bl[bu[ct] * 64 + ((h * 4 + quad + bu[ct]) & 7) * 8];
        #pragma unroll
        for (int rt = 0; rt < 4; ++rt)
          #pragma unroll
          for (int ct = 0; ct < 4; ++ct)
            acc[rt][ct] = __builtin_amdgcn_mfma_f32_16x16x32_bf16(
                af[rt], bfr[ct], acc[rt][ct], 0, 0, 0);
      }
    }

    // fused epilogue: C/D layout col=l16(+16ct), row=quad*4+r(+16rt)
    float part[4][4];
    #pragma unroll
    for (int rt = 0; rt < 4; ++rt)
      #pragma unroll
      for (int r = 0; r < 4; ++r) part[rt][r] = 0.0f;
    #pragma unroll
    for (int ct = 0; ct < 4; ++ct) {
      const int u = u0 + wc * 64 + ct * 16 + l16;
      const float qv = qq[b * U_SZ + u];
      const float vv = Vv[u];
      #pragma unroll
      for (int rt = 0; rt < 4; ++rt)
        #pragma unroll
        for (int r = 0; r < 4; ++r)
          part[rt][r] += fast_tanh(acc[rt][ct][r] + qv) * vv;
    }
    #pragma unroll
    for (int rt = 0; rt < 4; ++rt)
      #pragma unroll
      for (int r = 0; r < 4; ++r) {
        float p = part[rt][r];
        p += __shfl_xor(p, 1);
        p += __shfl_xor(p, 2);
        p += __shfl_xor(p, 4);
        p += __shfl_xor(p, 8);
        part[rt][r] = p;
      }
    if (l16 == 0) {
      #pragma unroll
      for (int rt = 0; rt < 4; ++rt)
        #pragma unroll
        for (int r = 0; r < 4; ++r)
          atomicAdd(&scoreS[wr * 64 + rt * 16 + quad * 4 + r], part[rt][r]);
    }
  }
  __syncthreads();
  if (tid < BM) score[m0 + tid] = scoreS[tid];
}

// ---------------------------------------------------------------------------
// softmax over T per batch (bv dropped: constant shift, softmax-invariant)
// ---------------------------------------------------------------------------
__global__ void k_softmax(const float* __restrict__ score, float* __restrict__ attn) {
  const int b = blockIdx.x;
  const int tid = threadIdx.x;   // 256
  __shared__ float wmax[4], wsum[4];
  const float* s = score + b * T_SZ;
  float v[8];
  float lmax = -INFINITY;
  #pragma unroll
  for (int i = 0; i < 8; ++i) { v[i] = s[tid + i * 256]; lmax = fmaxf(lmax, v[i]); }
  #pragma unroll
  for (int m = 1; m <= 32; m <<= 1) lmax = fmaxf(lmax, __shfl_xor(lmax, m));
  if ((tid & 63) == 0) wmax[tid >> 6] = lmax;
  __syncthreads();
  const float gmax = fmaxf(fmaxf(wmax[0], wmax[1]), fmaxf(wmax[2], wmax[3]));
  float lsum = 0.0f;
  #pragma unroll
  for (int i = 0; i < 8; ++i) { v[i] = __expf(v[i] - gmax); lsum += v[i]; }
  #pragma unroll
  for (int m = 1; m <= 32; m <<= 1) lsum += __shfl_xor(lsum, m);
  if ((tid & 63) == 0) wsum[tid >> 6] = lsum;
  __syncthreads();
  const float inv = 1.0f / (wsum[0] + wsum[1] + wsum[2] + wsum[3]);
  #pragma unroll
  for (int i = 0; i < 8; ++i) attn[b * T_SZ + tid + i * 256] = v[i] * inv;
}

// ---------------------------------------------------------------------------
// context[b][h] = sum_t attn[b][t] * enc[b][t][h]  (fp32 enc for precision)
// ---------------------------------------------------------------------------
__global__ void k_context(const float* __restrict__ enc, const float* __restrict__ attn,
                          float* __restrict__ ctx) {
  const int tcx = blockIdx.x;   // 0..7
  const int hc  = blockIdx.y;   // 0..3
  const int b   = blockIdx.z;   // 0..31
  const int h   = hc * 256 + threadIdx.x;
  const float* e = enc + ((size_t)b * T_SZ + tcx * 256) * H_SZ + h;
  const float* a = attn + b * T_SZ + tcx * 256;
  float a0 = 0, a1 = 0, a2 = 0, a3 = 0;
  for (int t = 0; t < 256; t += 4) {
    a0 += a[t]     * e[(size_t)t * H_SZ];
    a1 += a[t + 1] * e[(size_t)(t + 1) * H_SZ];
    a2 += a[t + 2] * e[(size_t)(t + 2) * H_SZ];
    a3 += a[t + 3] * e[(size_t)(t + 3) * H_SZ];
  }
  atomicAdd(&ctx[b * H_SZ + h], (a0 + a1) + (a2 + a3));
}

// ---------------------------------------------------------------------------
extern "C" void kernel_launch(void* const* d_in, const int* in_sizes, int n_in,
                              void* d_out, int out_size, void* d_ws, size_t ws_size,
                              hipStream_t stream) {
  const float* dec = (const float*)d_in[0];
  const float* enc = (const float*)d_in[1];
  const float* W1  = (const float*)d_in[2];
  const float* b1  = (const float*)d_in[3];
  const float* W2  = (const float*)d_in[4];
  const float* b2  = (const float*)d_in[5];
  const float* Vv  = (const float*)d_in[6];
  // d_in[7] = bv: constant shift inside softmax -> no effect on outputs.

  const size_t encb_bytes = (size_t)B_SZ * T_SZ * H_SZ * 2;   // 128 MB
  const size_t fast_need  = encb_bytes + (2u << 20) + (128u << 10) + (256u << 10);
  const bool fast = ws_size >= fast_need;

  char* ws = (char*)d_ws;
  unsigned short* encb = nullptr;
  unsigned short* W2t;
  float *qq, *score;
  if (fast) {
    encb  = (unsigned short*)ws;
    W2t   = (unsigned short*)(ws + encb_bytes);
    qq    = (float*)(ws + encb_bytes + (2u << 20));
    score = (float*)(ws + encb_bytes + (2u << 20) + (128u << 10));
  } else {
    W2t   = (unsigned short*)ws;
    qq    = (float*)(ws + (2u << 20));
    score = (float*)(ws + (2u << 20) + (128u << 10));
  }

  float* ctx  = (float*)d_out;                  // [32,1024]
  float* attn = (float*)d_out + B_SZ * H_SZ;    // [32,2048,1]

  hipMemsetAsync(ctx, 0, B_SZ * H_SZ * sizeof(float), stream);
  if (fast)
    k_cvt_enc<<<(B_SZ * T_SZ * H_SZ) / (256 * 8), 256, 0, stream>>>(enc, encb);
  k_prep_w2t<<<dim3(16, 16), 256, 0, stream>>>(W2, W2t);
  k_qq<<<dim3(16, 32), 256, 0, stream>>>(dec, W1, b1, b2, qq);
  if (fast)
    k_gemm_score<true><<<(B_SZ * T_SZ) / BM, 256, 0, stream>>>(encb, enc, W2t, qq, Vv, score);
  else
    k_gemm_score<false><<<(B_SZ * T_SZ) / BM, 256, 0, stream>>>(encb, enc, W2t, qq, Vv, score);
  k_softmax<<<32, 256, 0, stream>>>(score, attn);
  k_context<<<dim3(8, 4, 32), 256, 0, stream>>>(enc, attn, ctx);
}

// Round 3
// 636.928 us; speedup vs baseline: 1.6823x; 1.0276x over previous
//
#include <hip/hip_runtime.h>
#include <hip/hip_bf16.h>
#include <math.h>

#define B_SZ 32
#define T_SZ 2048
#define H_SZ 1024
#define U_SZ 1024

#define BM 64
#define BN 256
#define BK 64
#define UT_N (U_SZ / BN)   // 4

typedef __attribute__((ext_vector_type(8))) short bf16x8;   // 8 bf16 = 4 VGPRs
typedef __attribute__((ext_vector_type(4))) float f32x4;    // mfma 16x16 accumulator

// fp32 -> bf16 round-to-nearest-even
__device__ __forceinline__ unsigned int f2bf(float f) {
  union { float f; unsigned int u; } x; x.f = f;
  unsigned int r = x.u + 0x7FFFu + ((x.u >> 16) & 1u);
  return r >> 16;
}

__device__ __forceinline__ float bf2f(unsigned int lo16) {
  union { unsigned int u; float f; } x; x.u = lo16 << 16; return x.f;
}

// async global -> LDS, 16 B per lane. LDS dest = wave-uniform base + lane*16.
__device__ __forceinline__ void async_cp16(const unsigned short* g, unsigned short* l) {
  __builtin_amdgcn_global_load_lds(
      (const __attribute__((address_space(1))) unsigned int*)g,
      (__attribute__((address_space(3))) unsigned int*)l, 16, 0, 0);
}

__device__ __forceinline__ float fast_tanh(float x) {
  const float e = __expf(x + x);
  return (e - 1.0f) * __builtin_amdgcn_rcpf(e + 1.0f);
}

// ---------------------------------------------------------------------------
// Fused prep: [0,cvtN): enc fp32->bf16 | [cvtN,+256): W2->W2t | [+256,+768): qq
// One dispatch instead of three (launch-gap + overlap of BW-bound cvt with
// latency-bound qq).
// ---------------------------------------------------------------------------
__global__ __launch_bounds__(256) void k_prep(
    const float* __restrict__ enc, unsigned short* __restrict__ encb,
    const float* __restrict__ W2, unsigned short* __restrict__ W2t,
    const float* __restrict__ dec, const float* __restrict__ W1,
    const float* __restrict__ b1, const float* __restrict__ b2,
    float* __restrict__ qq, int cvtN)
{
  __shared__ char lds_raw[64 * 65 * 2];   // 8320 B, reused per branch
  const int bid = blockIdx.x;
  const int tid = threadIdx.x;

  if (bid < cvtN) {
    // ---- enc fp32 -> bf16, 8 elems/thread ----
    const size_t i = ((size_t)bid * 256 + tid) * 8;
    const float4 a = *(const float4*)(enc + i);
    const float4 b = *(const float4*)(enc + i + 4);
    uint4 o;
    o.x = f2bf(a.x) | (f2bf(a.y) << 16);
    o.y = f2bf(a.z) | (f2bf(a.w) << 16);
    o.z = f2bf(b.x) | (f2bf(b.y) << 16);
    o.w = f2bf(b.z) | (f2bf(b.w) << 16);
    *(uint4*)(encb + i) = o;
  } else if (bid < cvtN + 256) {
    // ---- W2 [H][U] -> W2t [U][H] bf16 ----
    unsigned short (*tile)[65] = (unsigned short(*)[65])lds_raw;
    const int idx = bid - cvtN;
    const int bu = idx & 15, bh = idx >> 4;
    const int tc = tid & 63, tr = tid >> 6;
    #pragma unroll
    for (int i = 0; i < 16; ++i) {
      const int hl = tr + i * 4;
      tile[tc][hl] = (unsigned short)f2bf(W2[(size_t)(bh * 64 + hl) * U_SZ + bu * 64 + tc]);
    }
    __syncthreads();
    #pragma unroll
    for (int i = 0; i < 16; ++i) {
      const int ul = tr + i * 4;
      W2t[(size_t)(bu * 64 + ul) * H_SZ + bh * 64 + tc] = tile[ul][tc];
    }
  } else {
    // ---- qq[b][u] = dec[b]·W1[:,u] + b1[u] + b2[u] ----
    float (*red)[64] = (float(*)[64])lds_raw;
    const int idx = bid - (cvtN + 256);    // 0..511
    const int ul = tid & 63;
    const int hq = tid >> 6;
    const int u  = (idx & 15) * 64 + ul;
    const int b  = idx >> 4;
    const float* dh = dec + b * H_SZ + hq * 256;
    const float* w  = W1 + (size_t)(hq * 256) * U_SZ + u;
    float acc = 0.0f;
    #pragma unroll 8
    for (int h = 0; h < 256; ++h) acc += dh[h] * w[(size_t)h * U_SZ];
    red[hq][ul] = acc;
    __syncthreads();
    if (tid < 64) {
      const float s = red[0][ul] + red[1][ul] + red[2][ul] + red[3][ul];
      qq[b * U_SZ + u] = s + b1[u] + b2[u];
    }
  }
}

// ---------------------------------------------------------------------------
// Fused GEMM + tanh·V reduce: score[m] = sum_u tanh((enc@W2)[m][u] + qq) * V[u]
// BM=64 rows/block, ut-loop over 4 BN=256 col tiles, BK=64. Grid 1024 blocks
// (4/CU by grid; 3/CU by LDS=40.5 KB) — occupancy fix vs round 2's 512.
// 4 waves: each computes all 64 rows x its 64-col slice (4x4 16x16x32 mfma).
// LDS swizzle (per round 2, measured 0 conflicts): row stride 128 B, 8x16 B
// chunks, stored chunk' = (chunk + row) & 7; staged via global_load_lds(16B)
// with the rotation applied on the global-address side.
// ---------------------------------------------------------------------------
template <bool PRE_BF16>
__global__ __launch_bounds__(256) void k_gemm_score(
    const unsigned short* __restrict__ encb,   // bf16 enc (fast path)
    const float* __restrict__ encf,            // fp32 enc (fallback path)
    const unsigned short* __restrict__ W2t,
    const float* __restrict__ qq, const float* __restrict__ Vv,
    float* __restrict__ score)
{
  __shared__ unsigned short Al[BM * BK];   // 8 KB
  __shared__ unsigned short Bl[BN * BK];   // 32 KB
  __shared__ float scoreS[BM];

  const int tid  = threadIdx.x;
  const int wave = tid >> 6;
  const int lane = tid & 63;
  const int quad = lane >> 4;
  const int l16  = lane & 15;
  const int m0   = blockIdx.x * BM;
  const int b    = m0 >> 11;       // 64 rows share one batch (2048 % 64 == 0)

  if (tid < BM) scoreS[tid] = 0.0f;

  // A staging: 512 slots of 16 B = 2 wave-insts per wave
  size_t aoff[2]; unsigned short* dstA[2];
  #pragma unroll
  for (int i = 0; i < 2; ++i) {
    const int slot = (i * 4 + wave) * 64 + lane;
    const int r = slot >> 3;                 // 0..63
    const int c = ((slot & 7) - r) & 7;      // source chunk (swizzle)
    aoff[i] = (size_t)(m0 + r) * H_SZ + c * 8;
    dstA[i] = &Al[(i * 4 + wave) * 512];
  }
  // B staging: 2048 slots = 8 wave-insts per wave
  size_t boff[8]; unsigned short* dstB[8];
  #pragma unroll
  for (int i = 0; i < 8; ++i) {
    const int slot = (i * 4 + wave) * 64 + lane;
    const int r = slot >> 3;                 // 0..255 (u_local)
    const int c = ((slot & 7) - r) & 7;
    boff[i] = (size_t)r * H_SZ + c * 8;
    dstB[i] = &Bl[(i * 4 + wave) * 512];
  }

  const int ar[4] = { 0 * 16 + l16, 1 * 16 + l16, 2 * 16 + l16, 3 * 16 + l16 };
  const int bu[4] = { wave * 64 + 0 * 16 + l16, wave * 64 + 1 * 16 + l16,
                      wave * 64 + 2 * 16 + l16, wave * 64 + 3 * 16 + l16 };

  for (int ut = 0; ut < UT_N; ++ut) {
    const int u0 = ut * BN;
    f32x4 acc[4][4];
    #pragma unroll
    for (int rt = 0; rt < 4; ++rt)
      #pragma unroll
      for (int ct = 0; ct < 4; ++ct)
        #pragma unroll
        for (int r = 0; r < 4; ++r) acc[rt][ct][r] = 0.0f;

    for (int kk = 0; kk < H_SZ; kk += BK) {
      __syncthreads();
      if constexpr (PRE_BF16) {
        #pragma unroll
        for (int i = 0; i < 2; ++i) async_cp16(encb + aoff[i] + kk, dstA[i]);
      } else {
        #pragma unroll
        for (int i = 0; i < 2; ++i) {
          const int slot = i * 256 + tid;
          const int r = slot >> 3;
          const int c = ((slot & 7) - r) & 7;
          const float* src = encf + (size_t)(m0 + r) * H_SZ + kk + c * 8;
          const float4 x = *(const float4*)src;
          const float4 y = *(const float4*)(src + 4);
          uint4 o;
          o.x = f2bf(x.x) | (f2bf(x.y) << 16);
          o.y = f2bf(x.z) | (f2bf(x.w) << 16);
          o.z = f2bf(y.x) | (f2bf(y.y) << 16);
          o.w = f2bf(y.z) | (f2bf(y.w) << 16);
          *(uint4*)&Al[slot * 8] = o;
        }
      }
      #pragma unroll
      for (int i = 0; i < 8; ++i)
        async_cp16(W2t + (size_t)u0 * H_SZ + boff[i] + kk, dstB[i]);
      __syncthreads();

      #pragma unroll
      for (int h = 0; h < 2; ++h) {
        bf16x8 af[4], bfr[4];
        #pragma unroll
        for (int rt = 0; rt < 4; ++rt)
          af[rt] = *(const bf16x8*)&Al[ar[rt] * 64 + ((h * 4 + quad + ar[rt]) & 7) * 8];
        #pragma unroll
        for (int ct = 0; ct < 4; ++ct)
          bfr[ct] = *(const bf16x8*)&Bl[bu[ct] * 64 + ((h * 4 + quad + bu[ct]) & 7) * 8];
        #pragma unroll
        for (int rt = 0; rt < 4; ++rt)
          #pragma unroll
          for (int ct = 0; ct < 4; ++ct)
            acc[rt][ct] = __builtin_amdgcn_mfma_f32_16x16x32_bf16(
                af[rt], bfr[ct], acc[rt][ct], 0, 0, 0);
      }
    }

    // fused epilogue: C/D layout col=l16(+16ct), row=quad*4+r(+16rt)
    float part[4][4];
    #pragma unroll
    for (int rt = 0; rt < 4; ++rt)
      #pragma unroll
      for (int r = 0; r < 4; ++r) part[rt][r] = 0.0f;
    #pragma unroll
    for (int ct = 0; ct < 4; ++ct) {
      const int u = u0 + wave * 64 + ct * 16 + l16;
      const float qv = qq[b * U_SZ + u];
      const float vv = Vv[u];
      #pragma unroll
      for (int rt = 0; rt < 4; ++rt)
        #pragma unroll
        for (int r = 0; r < 4; ++r)
          part[rt][r] += fast_tanh(acc[rt][ct][r] + qv) * vv;
    }
    #pragma unroll
    for (int rt = 0; rt < 4; ++rt)
      #pragma unroll
      for (int r = 0; r < 4; ++r) {
        float p = part[rt][r];
        p += __shfl_xor(p, 1);
        p += __shfl_xor(p, 2);
        p += __shfl_xor(p, 4);
        p += __shfl_xor(p, 8);
        part[rt][r] = p;
      }
    if (l16 == 0) {
      #pragma unroll
      for (int rt = 0; rt < 4; ++rt)
        #pragma unroll
        for (int r = 0; r < 4; ++r)
          atomicAdd(&scoreS[rt * 16 + quad * 4 + r], part[rt][r]);
    }
  }
  __syncthreads();
  if (tid < BM) score[m0 + tid] = scoreS[tid];
}

// ---------------------------------------------------------------------------
// softmax over T per batch (bv dropped: constant shift, softmax-invariant)
// ---------------------------------------------------------------------------
__global__ void k_softmax(const float* __restrict__ score, float* __restrict__ attn) {
  const int b = blockIdx.x;
  const int tid = threadIdx.x;   // 256
  __shared__ float wmax[4], wsum[4];
  const float* s = score + b * T_SZ;
  float v[8];
  float lmax = -INFINITY;
  #pragma unroll
  for (int i = 0; i < 8; ++i) { v[i] = s[tid + i * 256]; lmax = fmaxf(lmax, v[i]); }
  #pragma unroll
  for (int m = 1; m <= 32; m <<= 1) lmax = fmaxf(lmax, __shfl_xor(lmax, m));
  if ((tid & 63) == 0) wmax[tid >> 6] = lmax;
  __syncthreads();
  const float gmax = fmaxf(fmaxf(wmax[0], wmax[1]), fmaxf(wmax[2], wmax[3]));
  float lsum = 0.0f;
  #pragma unroll
  for (int i = 0; i < 8; ++i) { v[i] = __expf(v[i] - gmax); lsum += v[i]; }
  #pragma unroll
  for (int m = 1; m <= 32; m <<= 1) lsum += __shfl_xor(lsum, m);
  if ((tid & 63) == 0) wsum[tid >> 6] = lsum;
  __syncthreads();
  const float inv = 1.0f / (wsum[0] + wsum[1] + wsum[2] + wsum[3]);
  #pragma unroll
  for (int i = 0; i < 8; ++i) attn[b * T_SZ + tid + i * 256] = v[i] * inv;
}

// ---------------------------------------------------------------------------
// context[b][h] = sum_t attn[b][t] * enc[b][t][h] — bf16 enc, 2 h per thread
// ---------------------------------------------------------------------------
__global__ void k_context_bf16(const unsigned short* __restrict__ encb,
                               const float* __restrict__ attn, float* __restrict__ ctx) {
  const int tcx = blockIdx.x;   // 0..7
  const int hc  = blockIdx.y;   // 0..1
  const int b   = blockIdx.z;   // 0..31
  const int h0  = hc * 512 + threadIdx.x * 2;
  const unsigned short* e = encb + ((size_t)b * T_SZ + tcx * 256) * H_SZ + h0;
  const float* a = attn + b * T_SZ + tcx * 256;
  float c0 = 0, c1 = 0;
  #pragma unroll 4
  for (int t = 0; t < 256; ++t) {
    const unsigned int v = *(const unsigned int*)&e[(size_t)t * H_SZ];
    c0 += a[t] * bf2f(v & 0xFFFFu);
    c1 += a[t] * bf2f(v >> 16);
  }
  atomicAdd(&ctx[b * H_SZ + h0],     c0);
  atomicAdd(&ctx[b * H_SZ + h0 + 1], c1);
}

__global__ void k_context_f32(const float* __restrict__ enc,
                              const float* __restrict__ attn, float* __restrict__ ctx) {
  const int tcx = blockIdx.x, hc = blockIdx.y, b = blockIdx.z;
  const int h = hc * 256 + threadIdx.x;
  const float* e = enc + ((size_t)b * T_SZ + tcx * 256) * H_SZ + h;
  const float* a = attn + b * T_SZ + tcx * 256;
  float a0 = 0, a1 = 0, a2 = 0, a3 = 0;
  for (int t = 0; t < 256; t += 4) {
    a0 += a[t]     * e[(size_t)t * H_SZ];
    a1 += a[t + 1] * e[(size_t)(t + 1) * H_SZ];
    a2 += a[t + 2] * e[(size_t)(t + 2) * H_SZ];
    a3 += a[t + 3] * e[(size_t)(t + 3) * H_SZ];
  }
  atomicAdd(&ctx[b * H_SZ + h], (a0 + a1) + (a2 + a3));
}

// ---------------------------------------------------------------------------
extern "C" void kernel_launch(void* const* d_in, const int* in_sizes, int n_in,
                              void* d_out, int out_size, void* d_ws, size_t ws_size,
                              hipStream_t stream) {
  const float* dec = (const float*)d_in[0];
  const float* enc = (const float*)d_in[1];
  const float* W1  = (const float*)d_in[2];
  const float* b1  = (const float*)d_in[3];
  const float* W2  = (const float*)d_in[4];
  const float* b2  = (const float*)d_in[5];
  const float* Vv  = (const float*)d_in[6];
  // d_in[7] = bv: constant shift inside softmax -> no effect on outputs.

  const size_t encb_bytes = (size_t)B_SZ * T_SZ * H_SZ * 2;   // 128 MB
  const size_t fast_need  = encb_bytes + (2u << 20) + (128u << 10) + (256u << 10);
  const bool fast = ws_size >= fast_need;

  char* ws = (char*)d_ws;
  unsigned short* encb = nullptr;
  unsigned short* W2t;
  float *qq, *score;
  if (fast) {
    encb  = (unsigned short*)ws;
    W2t   = (unsigned short*)(ws + encb_bytes);
    qq    = (float*)(ws + encb_bytes + (2u << 20));
    score = (float*)(ws + encb_bytes + (2u << 20) + (128u << 10));
  } else {
    W2t   = (unsigned short*)ws;
    qq    = (float*)(ws + (2u << 20));
    score = (float*)(ws + (2u << 20) + (128u << 10));
  }

  float* ctx  = (float*)d_out;                  // [32,1024]
  float* attn = (float*)d_out + B_SZ * H_SZ;    // [32,2048,1]

  hipMemsetAsync(ctx, 0, B_SZ * H_SZ * sizeof(float), stream);
  const int cvtN = fast ? (B_SZ * T_SZ * H_SZ) / (256 * 8) : 0;   // 2048 or 0
  k_prep<<<cvtN + 256 + 512, 256, 0, stream>>>(enc, encb, W2, W2t,
                                               dec, W1, b1, b2, qq, cvtN);
  if (fast)
    k_gemm_score<true><<<(B_SZ * T_SZ) / BM, 256, 0, stream>>>(encb, enc, W2t, qq, Vv, score);
  else
    k_gemm_score<false><<<(B_SZ * T_SZ) / BM, 256, 0, stream>>>(encb, enc, W2t, qq, Vv, score);
  k_softmax<<<32, 256, 0, stream>>>(score, attn);
  if (fast)
    k_context_bf16<<<dim3(8, 2, 32), 256, 0, stream>>>(encb, attn, ctx);
  else
    k_context_f32<<<dim3(8, 4, 32), 256, 0, stream>>>(enc, attn, ctx);
}